// Round 3
// baseline (671.848 us; speedup 1.0000x reference)
//
#include <hip/hip_runtime.h>
#include <hip/hip_bf16.h>
#include <math.h>

// Problem constants (B=4, N=2048, D=1024, E=8, H=4096, C = int(2048*1.25//8)=320)
#define B_ 4
#define N_ 2048
#define D_ 1024
#define E_ 8
#define H_ 4096
#define C_ 320
#define M_ (B_*C_)        // 1280 rows per expert in the grouped GEMMs

typedef __attribute__((ext_vector_type(8))) short short8;   // 8 bf16 = 4 VGPRs (MFMA A/B frag)
typedef __attribute__((ext_vector_type(4))) float floatx4;  // MFMA C/D frag

__device__ __forceinline__ unsigned short f2bf(float f) {
  unsigned u = __builtin_bit_cast(unsigned, f);
  u += 0x7fffu + ((u >> 16) & 1u);          // RNE; inputs are tame (no NaN/Inf)
  return (unsigned short)(u >> 16);
}

// fast tanh-gelu via v_exp_f32: tanh(u) = 1 - 2/(exp(2u)+1). |err| ~1e-6, buried by bf16.
__device__ __forceinline__ float gelu_fast(float x) {
  float u = 0.7978845608028654f * (x + 0.044715f * x * x * x);
  float t = 1.f - 2.f / (__expf(2.f * u) + 1.f);
  return 0.5f * x * (1.f + t);
}

// async global -> LDS, 16 B per lane. LDS dest = wave-uniform base + lane*16 (m97/m104).
__device__ __forceinline__ void gload_lds16(const unsigned short* g, unsigned short* l) {
  __builtin_amdgcn_global_load_lds(
      (const __attribute__((address_space(1))) unsigned int*)g,
      (__attribute__((address_space(3))) unsigned int*)l, 16, 0, 0);
}

// ---------------------------------------------------------------------------
// K1: router. One wave per token; fp64 accumulation to avoid argmax flips vs
// the numpy fp32 reference. stats: [0..31]=count[b*8+e], [32..63]=proxy, [64]=z^2 sum
// ---------------------------------------------------------------------------
__global__ __launch_bounds__(256) void router_kernel(
    const float* __restrict__ x, const float* __restrict__ wr,
    int* __restrict__ idx_buf, float* __restrict__ gate_buf,
    float* __restrict__ stats)
{
  int lane  = threadIdx.x & 63;
  int wave  = threadIdx.x >> 6;
  int token = blockIdx.x * 4 + wave;        // 0..8191
  int b     = token >> 11;                  // N_=2048

  const float* xp = x + (size_t)token * D_ + lane * 16;
  float xv[16];
#pragma unroll
  for (int i = 0; i < 4; i++) {
    float4 v = ((const float4*)xp)[i];
    xv[i*4+0]=v.x; xv[i*4+1]=v.y; xv[i*4+2]=v.z; xv[i*4+3]=v.w;
  }
  double acc[8];
#pragma unroll
  for (int e = 0; e < 8; e++) acc[e] = 0.0;
  const float* wp = wr + (size_t)(lane * 16) * E_;   // w_router is [D][E]
#pragma unroll
  for (int i = 0; i < 16; i++) {
    float xs = xv[i];
#pragma unroll
    for (int e = 0; e < 8; e++) acc[e] += (double)xs * (double)wp[i*8 + e];
  }
  for (int off = 32; off > 0; off >>= 1) {
#pragma unroll
    for (int e = 0; e < 8; e++) acc[e] += __shfl_xor(acc[e], off, 64);
  }

  float l[8];
#pragma unroll
  for (int e = 0; e < 8; e++) l[e] = (float)acc[e];
  float m = l[0]; int best = 0;
#pragma unroll
  for (int e = 1; e < 8; e++) if (l[e] > m) { m = l[e]; best = e; }   // first-max tiebreak
  float p[8], sum = 0.f;
#pragma unroll
  for (int e = 0; e < 8; e++) { p[e] = expf(l[e] - m); sum += p[e]; }
  float inv = 1.f / sum;
#pragma unroll
  for (int e = 0; e < 8; e++) p[e] *= inv;
  float z    = m + logf(sum);
  float gate = inv;                      // softmax at argmax = exp(0)/sum

  __shared__ float s_cnt[8], s_prox[8], s_zsq[1];
  if (threadIdx.x < 8)  { s_cnt[threadIdx.x] = 0.f; s_prox[threadIdx.x] = 0.f; }
  if (threadIdx.x == 8) s_zsq[0] = 0.f;
  __syncthreads();
  if (lane == 0) {
    idx_buf[token]  = best;
    gate_buf[token] = gate;
    atomicAdd(&s_zsq[0], z * z);
    atomicAdd(&s_cnt[best], 1.f);
#pragma unroll
    for (int e = 0; e < 8; e++) atomicAdd(&s_prox[e], p[e]);
  }
  __syncthreads();
  if (threadIdx.x < 8) {
    atomicAdd(&stats[b*8 + threadIdx.x],      s_cnt[threadIdx.x]);
    atomicAdd(&stats[32 + b*8 + threadIdx.x], s_prox[threadIdx.x]);
  }
  if (threadIdx.x == 8) atomicAdd(&stats[64], s_zsq[0]);
}

// ---------------------------------------------------------------------------
// K2: per-(b,e) capacity scan + loss finalize (folded; stats ready since the
// router kernel completed before this launch).
// ---------------------------------------------------------------------------
__global__ __launch_bounds__(64) void pos_kernel(
    const int* __restrict__ idx_buf, int* __restrict__ slot_token,
    const float* __restrict__ stats, float* __restrict__ loss_out)
{
  int be = blockIdx.x;                 // 0..31
  int b = be >> 3, e = be & 7;
  int lane = threadIdx.x;
  int base = 0;
  int* out = slot_token + (size_t)(e * B_ + b) * C_;
  for (int n0 = 0; n0 < N_; n0 += 64) {
    int n = n0 + lane;
    bool match = (idx_buf[b * N_ + n] == e);
    unsigned long long mask = __ballot(match);
    int my = base + __popcll(mask & ((1ull << lane) - 1ull));
    if (match && my < C_) out[my] = b * N_ + n;
    base += __popcll(mask);
  }
  if (be == 0 && lane == 0) {
    float aux = 0.f;
    for (int i = 0; i < 32; i++) aux += stats[i] * stats[32 + i];
    aux *= 64.f / ((float)B_ * (float)N_ * (float)N_);   // E^2 / (B*N*N)
    loss_out[0] = aux;
    loss_out[1] = stats[64] / (float)(B_ * N_);
  }
}

// ---------------------------------------------------------------------------
// K3: gather+cast x rows into xe bf16 [E][M_][D]. One block per slot row.
// ---------------------------------------------------------------------------
__global__ __launch_bounds__(256) void gather_kernel(
    const float* __restrict__ x, const int* __restrict__ slot_token,
    unsigned short* __restrict__ xe)
{
  int row = blockIdx.x;                // 0..E*M_-1  == (e*B+b)*C + c
  int t = slot_token[row];
  int col = threadIdx.x * 4;
  ushort4 o;
  if (t >= 0) {
    float4 v = *(const float4*)(x + (size_t)t * D_ + col);
    o.x = f2bf(v.x); o.y = f2bf(v.y); o.z = f2bf(v.z); o.w = f2bf(v.w);
  } else {
    o.x = 0; o.y = 0; o.z = 0; o.w = 0;
  }
  *(ushort4*)(xe + (size_t)row * D_ + col) = o;
}

// ---------------------------------------------------------------------------
// K4: transpose+cast weights: in fp32 [E][R][Cc] -> out bf16 [E][Cc][R].
// 64x64 tile; coalesced reads/writes; LDS padded to 65.
// ---------------------------------------------------------------------------
__global__ __launch_bounds__(256) void transcast_kernel(
    const float* __restrict__ in, unsigned short* __restrict__ out, int R, int Cc)
{
  int e = blockIdx.z;
  const float* pin = in + (size_t)e * R * Cc;
  unsigned short* pout = out + (size_t)e * R * Cc;
  __shared__ float T[64][65];
  int r0 = blockIdx.y * 64, c0 = blockIdx.x * 64;
  {
    int row = threadIdx.x >> 2;               // 0..63
    int cb  = (threadIdx.x & 3) * 4;          // 0,4,8,12
#pragma unroll
    for (int p = 0; p < 4; p++) {
      int col = cb + p * 16;
      float4 v = *(const float4*)(pin + (size_t)(r0 + row) * Cc + c0 + col);
      T[row][col+0] = v.x; T[row][col+1] = v.y; T[row][col+2] = v.z; T[row][col+3] = v.w;
    }
  }
  __syncthreads();
  {
    int ocb = threadIdx.x >> 4;               // 0..15
    int or4 = (threadIdx.x & 15) * 4;         // 0..60
#pragma unroll
    for (int p = 0; p < 4; p++) {
      int oc = ocb + p * 16;
      ushort4 o;
      o.x = f2bf(T[or4+0][oc]); o.y = f2bf(T[or4+1][oc]);
      o.z = f2bf(T[or4+2][oc]); o.w = f2bf(T[or4+3][oc]);
      *(ushort4*)(pout + (size_t)(c0 + oc) * R + r0 + or4) = o;
    }
  }
}

// ---------------------------------------------------------------------------
// K5: grouped GEMM, 256x256, R3: ONE-PHASE REGISTER READ-AHEAD.
//
// R2 evidence: deep global prefetch changed nothing (153 vs 155 us; MfmaUtil
// ~22%, VALUBusy ~10%, conflicts 0) -> the stall is the lockstep
// {ds_read burst -> lgkmcnt(0) -> MFMA burst} serialization: LDS pipe and
// matrix pipe never overlap. Fix: each phase issues the NEXT phase's
// fragment reads, then MFMAs on fragments read a phase earlier, with COUNTED
// lgkm waits. LDS reads drain on the LDS pipe while the matrix pipe runs.
//
// Quadrant order per K-tile (each acc's K order unchanged -> bitwise-same):
//   P0: A0xB0 -> acc[0-3][0-1]   reads B1       lgkmcnt(4)
//   P1: A0xB1 -> acc[0-3][2-3]   reads A1       lgkmcnt(8)
//   BAR1  (all B1 drained -> Bs[cur] reusable)
//   P2: A1xB0 -> acc[4-7][0-1]   stage B(t+2)->Bs[cur]   lgkmcnt(0)
//       vmcnt(4)  (drains t+1's 8 staged loads; t+2's B stays in flight)
//   BAR2  (As[cur] reusable; buf[nxt] published to all waves)
//   P3: A1xB1 -> acc[4-7][2-3]   stage A(t+2)->As[cur];
//       reads A0,B0 of t+1 from buf[nxt]        (no wait: MFMA indep)
// Only 2 barriers per K-tile (vs 8) -- the other 6 were not correctness-
// relevant (proven via drain-before-barrier chain).
//
// T2 swizzle unchanged (R1-verified: SQ_LDS_BANK_CONFLICT = 0).
// Staging addrs: uniform SGPR bases + one 32-bit VGPR offset per operand
// (frees ~14 VGPR; frag double-residency costs +32).
// ---------------------------------------------------------------------------
template<int EPI>
__global__ __launch_bounds__(512, 2) void gemm_kernel(
    const unsigned short* __restrict__ A,    // [E][M][K] bf16
    const unsigned short* __restrict__ BT,   // [E][Nn][K] bf16
    const float* __restrict__ bias,          // [E][Nn] fp32
    unsigned short* __restrict__ Hout,       // EPI=0
    float* __restrict__ Out,                 // EPI=1 (pre-zeroed d_out)
    const int* __restrict__ slot_token,      // EPI=1
    const float* __restrict__ gate_buf,      // EPI=1
    int M, int K, int Nn, int MT)            // MT = M/256 tiles
{
  int e  = blockIdx.x & 7;                  // expert == XCD (round-robin map)
  int s  = blockIdx.x >> 3;                 // slot within expert
  int m0 = (s % MT) * 256;                  // m-inner
  int n0 = (s / MT) * 256;                  // n-outer
  const unsigned short* Ae = A  + (size_t)e * M  * K;
  const unsigned short* Be = BT + (size_t)e * Nn * K;

  __shared__ __align__(16) unsigned short As[2][256 * 64];   // 64 KiB
  __shared__ __align__(16) unsigned short Bs[2][256 * 64];   // 64 KiB
  __shared__ int   s_tok[256];
  __shared__ float s_gate[256];

  int tid  = threadIdx.x;
  int lane = tid & 63;
  int w    = tid >> 6;                      // wave 0..7
  int wm   = (w >> 2) * 128;                // wave row base within tile
  int wn   = (w & 3) * 64;                  // wave col base within tile
  int lr   = lane & 15;
  int quad = lane >> 4;
  // swizzled read chunk offsets (elements) for kk=0 / kk=1
  int c0 = (((quad    ) ^ (lane & 7)) << 3);
  int c1 = (((quad + 4) ^ (lane & 7)) << 3);

  if constexpr (EPI == 1) {
    if (tid < 256) {
      int t = slot_token[(size_t)e * M + m0 + tid];
      s_tok[tid]  = t;
      s_gate[tid] = (t >= 0) ? gate_buf[t] : 0.f;
    }
  }

  floatx4 acc[8][4];
#pragma unroll
  for (int i = 0; i < 8; i++)
#pragma unroll
    for (int j = 0; j < 4; j++) acc[i][j] = (floatx4){0.f, 0.f, 0.f, 0.f};

  // Staging: lane -> row base + (lane>>3), src chunk = (lane&7)^(row&7)
  // [inverse swizzle]; LDS dest linear. Uniform SGPR base + 32-bit VGPR
  // byte offset (advances 128 B per K-tile).
  int rrow = lane >> 3;
  int sch  = ((lane & 7) ^ rrow) << 3;      // source chunk offset in elements
  unsigned kA   = (unsigned)K * 2;          // bytes per row
  unsigned aoff = (unsigned)(m0 + w*16 + rrow) * kA + (unsigned)sch * 2;
  unsigned boff = (unsigned)(n0 + w*16 + rrow) * kA + (unsigned)sch * 2;
  const char* AeC = (const char*)Ae;
  const char* BeC = (const char*)Be;

#define STAGE_A(dbuf) do { \
    gload_lds16((const unsigned short*)(AeC + aoff),            &As[dbuf][(w*16    ) * 64]); \
    gload_lds16((const unsigned short*)(AeC + aoff +   8*kA),   &As[dbuf][(w*16 + 8) * 64]); \
    gload_lds16((const unsigned short*)(AeC + aoff + 128*kA),   &As[dbuf][(128 + w*16    ) * 64]); \
    gload_lds16((const unsigned short*)(AeC + aoff + 136*kA),   &As[dbuf][(128 + w*16 + 8) * 64]); \
    aoff += 128; } while (0)
#define STAGE_B(dbuf) do { \
    gload_lds16((const unsigned short*)(BeC + boff),            &Bs[dbuf][(w*16    ) * 64]); \
    gload_lds16((const unsigned short*)(BeC + boff +   8*kA),   &Bs[dbuf][(w*16 + 8) * 64]); \
    gload_lds16((const unsigned short*)(BeC + boff + 128*kA),   &Bs[dbuf][(128 + w*16    ) * 64]); \
    gload_lds16((const unsigned short*)(BeC + boff + 136*kA),   &Bs[dbuf][(128 + w*16 + 8) * 64]); \
    boff += 128; } while (0)

  short8 a0[4][2], a1[4][2], b0[2][2], b1[2][2];

#define READ_A0(buf) do { _Pragma("unroll") \
    for (int m_ = 0; m_ < 4; ++m_) { int row = wm + m_ * 16 + lr; \
      a0[m_][0] = *(const short8*)&As[buf][row * 64 + c0]; \
      a0[m_][1] = *(const short8*)&As[buf][row * 64 + c1]; } } while (0)
#define READ_A1(buf) do { _Pragma("unroll") \
    for (int m_ = 0; m_ < 4; ++m_) { int row = wm + 64 + m_ * 16 + lr; \
      a1[m_][0] = *(const short8*)&As[buf][row * 64 + c0]; \
      a1[m_][1] = *(const short8*)&As[buf][row * 64 + c1]; } } while (0)
#define READ_B0(buf) do { _Pragma("unroll") \
    for (int n_ = 0; n_ < 2; ++n_) { int row = wn + n_ * 16 + lr; \
      b0[n_][0] = *(const short8*)&Bs[buf][row * 64 + c0]; \
      b0[n_][1] = *(const short8*)&Bs[buf][row * 64 + c1]; } } while (0)
#define READ_B1(buf) do { _Pragma("unroll") \
    for (int n_ = 0; n_ < 2; ++n_) { int row = wn + 32 + n_ * 16 + lr; \
      b1[n_][0] = *(const short8*)&Bs[buf][row * 64 + c0]; \
      b1[n_][1] = *(const short8*)&Bs[buf][row * 64 + c1]; } } while (0)

#define SB0 __builtin_amdgcn_sched_barrier(0)

  int nt = K >> 6;                          // K-tiles of 64
  // Prologue: t0 -> buf0, t1 -> buf1 (order B1 then A1 matches steady state);
  // drain t0, publish, read t0's A0+B0 frags.
  STAGE_A(0); STAGE_B(0);
  if (nt > 1) {
    STAGE_B(1); STAGE_A(1);
    asm volatile("s_waitcnt vmcnt(8)" ::: "memory");
  } else {
    asm volatile("s_waitcnt vmcnt(0)" ::: "memory");
  }
  __builtin_amdgcn_s_barrier();
  READ_A0(0); READ_B0(0);

  int cur = 0;
  for (int t = 0; t < nt; ++t) {
    int nxt = cur ^ 1;
    // ---------------- P0: MFMA A0xB0 ; read B1 ----------------
    READ_B1(cur);
    SB0;
    asm volatile("s_waitcnt lgkmcnt(4)" ::: "memory");   // drain A0,B0 (12)
    SB0;
    __builtin_amdgcn_s_setprio(1);
#pragma unroll
    for (int m = 0; m < 4; ++m)
#pragma unroll
      for (int n = 0; n < 2; ++n) {
        acc[m][n] = __builtin_amdgcn_mfma_f32_16x16x32_bf16(a0[m][0], b0[n][0], acc[m][n], 0, 0, 0);
        acc[m][n] = __builtin_amdgcn_mfma_f32_16x16x32_bf16(a0[m][1], b0[n][1], acc[m][n], 0, 0, 0);
      }
    __builtin_amdgcn_s_setprio(0);
    // ---------------- P1: MFMA A0xB1 ; read A1 ----------------
    READ_A1(cur);
    SB0;
    asm volatile("s_waitcnt lgkmcnt(8)" ::: "memory");   // drain B1 (4)
    SB0;
    __builtin_amdgcn_s_setprio(1);
#pragma unroll
    for (int m = 0; m < 4; ++m)
#pragma unroll
      for (int n = 0; n < 2; ++n) {
        acc[m][n+2] = __builtin_amdgcn_mfma_f32_16x16x32_bf16(a0[m][0], b1[n][0], acc[m][n+2], 0, 0, 0);
        acc[m][n+2] = __builtin_amdgcn_mfma_f32_16x16x32_bf16(a0[m][1], b1[n][1], acc[m][n+2], 0, 0, 0);
      }
    __builtin_amdgcn_s_setprio(0);
    __builtin_amdgcn_s_barrier();          // BAR1: all B1 drained -> Bs[cur] free
    // ---------------- P2: MFMA A1xB0 ; stage B(t+2) ----------------
    if (t + 2 < nt) STAGE_B(cur);
    SB0;
    asm volatile("s_waitcnt lgkmcnt(0)" ::: "memory");   // drain A1 (8)
    SB0;
    __builtin_amdgcn_s_setprio(1);
#pragma unroll
    for (int m = 0; m < 4; ++m)
#pragma unroll
      for (int n = 0; n < 2; ++n) {
        acc[m+4][n] = __builtin_amdgcn_mfma_f32_16x16x32_bf16(a1[m][0], b0[n][0], acc[m+4][n], 0, 0, 0);
        acc[m+4][n] = __builtin_amdgcn_mfma_f32_16x16x32_bf16(a1[m][1], b0[n][1], acc[m+4][n], 0, 0, 0);
      }
    __builtin_amdgcn_s_setprio(0);
    // Counted: drain t+1's 8 staged loads; keep t+2's B (4) in flight.
    if (t + 2 < nt)      asm volatile("s_waitcnt vmcnt(4)" ::: "memory");
    else if (t + 1 < nt) asm volatile("s_waitcnt vmcnt(0)" ::: "memory");
    __builtin_amdgcn_s_barrier();          // BAR2: As[cur] free; buf[nxt] published
    // ---------------- P3: MFMA A1xB1 ; stage A(t+2); read t+1 A0,B0 --------
    if (t + 2 < nt) STAGE_A(cur);
    if (t + 1 < nt) { READ_A0(nxt); READ_B0(nxt); }
    SB0;
    __builtin_amdgcn_s_setprio(1);
#pragma unroll
    for (int m = 0; m < 4; ++m)
#pragma unroll
      for (int n = 0; n < 2; ++n) {
        acc[m+4][n+2] = __builtin_amdgcn_mfma_f32_16x16x32_bf16(a1[m][0], b1[n][0], acc[m+4][n+2], 0, 0, 0);
        acc[m+4][n+2] = __builtin_amdgcn_mfma_f32_16x16x32_bf16(a1[m][1], b1[n][1], acc[m+4][n+2], 0, 0, 0);
      }
    __builtin_amdgcn_s_setprio(0);
    cur = nxt;
  }
#undef STAGE_A
#undef STAGE_B
#undef READ_A0
#undef READ_A1
#undef READ_B0
#undef READ_B1
#undef SB0

  // Epilogue. C/D layout: col = lane&15, row = quad*4 + reg (m89-verified).
#pragma unroll
  for (int m = 0; m < 8; ++m) {
    int rloc = wm + m * 16 + quad * 4;      // block-local row base
#pragma unroll
    for (int n = 0; n < 4; ++n) {
      int col = n0 + wn + n * 16 + lr;
      float bz = bias[(size_t)e * Nn + col];
      if constexpr (EPI == 0) {
        size_t base = (size_t)e * M * Nn + (size_t)(m0 + rloc) * Nn + col;
#pragma unroll
        for (int r = 0; r < 4; r++)
          Hout[base + (size_t)r * Nn] = f2bf(gelu_fast(acc[m][n][r] + bz));
      } else {
#pragma unroll
        for (int r = 0; r < 4; r++) {
          int t = s_tok[rloc + r];
          if (t >= 0)
            Out[(size_t)t * D_ + col] = s_gate[rloc + r] * (acc[m][n][r] + bz);
        }
      }
    }
  }
}

// ---------------------------------------------------------------------------
extern "C" void kernel_launch(void* const* d_in, const int* in_sizes, int n_in,
                              void* d_out, int out_size, void* d_ws, size_t ws_size,
                              hipStream_t stream)
{
  (void)in_sizes; (void)n_in; (void)ws_size;
  const float* x  = (const float*)d_in[0];
  const float* wr = (const float*)d_in[1];
  const float* w1 = (const float*)d_in[2];
  const float* b1 = (const float*)d_in[3];
  const float* w2 = (const float*)d_in[4];
  const float* b2 = (const float*)d_in[5];
  float* out = (float*)d_out;

  // ws layout (~172 MB total)
  char* ws = (char*)d_ws;
  int*   idx_buf  = (int*)(ws + 0);              // 32 KB
  float* gate_buf = (float*)(ws + 32768);        // 32 KB
  float* stats    = (float*)(ws + 65536);        // 1 KB
  int*   slot_tok = (int*)(ws + 66560);          // 40 KB
  unsigned short* xe  = (unsigned short*)(ws + 107520);    // 20.97 MB
  unsigned short* wbf = (unsigned short*)(ws + 21079040);  // 67.1 MB (w1 then w2)
  unsigned short* hbf = (unsigned short*)(ws + 88187904);  // 83.9 MB; end 172073984

  hipMemsetAsync(d_out, 0, (size_t)out_size * 4, stream);       // dropped tokens -> 0
  hipMemsetAsync(stats, 0, 1024, stream);
  hipMemsetAsync(slot_tok, 0xFF, (size_t)E_ * B_ * C_ * 4, stream);  // -1 = empty slot

  router_kernel<<<(B_ * N_) / 4, 256, 0, stream>>>(x, wr, idx_buf, gate_buf, stats);
  pos_kernel<<<B_ * E_, 64, 0, stream>>>(idx_buf, slot_tok, stats,
                                         out + (size_t)B_ * N_ * D_);
  gather_kernel<<<E_ * M_, 256, 0, stream>>>(x, slot_tok, xe);

  // w1 [E][D][H] -> wbf [E][H][D]
  transcast_kernel<<<dim3(H_ / 64, D_ / 64, E_), 256, 0, stream>>>(w1, wbf, D_, H_);
  // h = gelu(xe @ w1 + b1): M=1280, K=1024, Nn=4096; grid = E * (16n x 5m), 512 thr
  gemm_kernel<0><<<E_ * (H_ / 256) * (M_ / 256), 512, 0, stream>>>(
      xe, wbf, b1, hbf, nullptr, nullptr, nullptr, M_, D_, H_, M_ / 256);
  // w2 [E][H][D] -> wbf [E][D][H]  (reuse buffer; stream-serialized after GEMM1)
  transcast_kernel<<<dim3(D_ / 64, H_ / 64, E_), 256, 0, stream>>>(w2, wbf, H_, D_);
  // out = gate * (h @ w2 + b2): M=1280, K=4096, Nn=1024; grid = E * (4n x 5m)
  gemm_kernel<1><<<E_ * (D_ / 256) * (M_ / 256), 512, 0, stream>>>(
      hbf, wbf, b2, nullptr, out, slot_tok, gate_buf, M_, H_, D_, M_ / 256);
}

// Round 5
// 621.901 us; speedup vs baseline: 1.0803x; 1.0803x over previous
//
#include <hip/hip_runtime.h>
#include <hip/hip_bf16.h>
#include <math.h>

// Problem constants (B=4, N=2048, D=1024, E=8, H=4096, C = int(2048*1.25//8)=320)
#define B_ 4
#define N_ 2048
#define D_ 1024
#define E_ 8
#define H_ 4096
#define C_ 320
#define M_ (B_*C_)        // 1280 rows per expert in the grouped GEMMs

typedef __attribute__((ext_vector_type(8))) short short8;   // 8 bf16 = 4 VGPRs (MFMA A/B frag)
typedef __attribute__((ext_vector_type(4))) float floatx4;  // MFMA C/D frag

__device__ __forceinline__ unsigned short f2bf(float f) {
  unsigned u = __builtin_bit_cast(unsigned, f);
  u += 0x7fffu + ((u >> 16) & 1u);          // RNE; inputs are tame (no NaN/Inf)
  return (unsigned short)(u >> 16);
}

// fast tanh-gelu via v_exp_f32: tanh(u) = 1 - 2/(exp(2u)+1). |err| ~1e-6, buried by bf16.
__device__ __forceinline__ float gelu_fast(float x) {
  float u = 0.7978845608028654f * (x + 0.044715f * x * x * x);
  float t = 1.f - 2.f / (__expf(2.f * u) + 1.f);
  return 0.5f * x * (1.f + t);
}

// async global -> LDS, 16 B per lane. LDS dest = wave-uniform base + lane*16 (m97/m104).
__device__ __forceinline__ void gload_lds16(const unsigned short* g, unsigned short* l) {
  __builtin_amdgcn_global_load_lds(
      (const __attribute__((address_space(1))) unsigned int*)g,
      (__attribute__((address_space(3))) unsigned int*)l, 16, 0, 0);
}

// ---------------------------------------------------------------------------
// K1: router. One wave per token; fp64 accumulation to avoid argmax flips vs
// the numpy fp32 reference. stats: [0..31]=count[b*8+e], [32..63]=proxy, [64]=z^2 sum
// ---------------------------------------------------------------------------
__global__ __launch_bounds__(256) void router_kernel(
    const float* __restrict__ x, const float* __restrict__ wr,
    int* __restrict__ idx_buf, float* __restrict__ gate_buf,
    float* __restrict__ stats)
{
  int lane  = threadIdx.x & 63;
  int wave  = threadIdx.x >> 6;
  int token = blockIdx.x * 4 + wave;        // 0..8191
  int b     = token >> 11;                  // N_=2048

  const float* xp = x + (size_t)token * D_ + lane * 16;
  float xv[16];
#pragma unroll
  for (int i = 0; i < 4; i++) {
    float4 v = ((const float4*)xp)[i];
    xv[i*4+0]=v.x; xv[i*4+1]=v.y; xv[i*4+2]=v.z; xv[i*4+3]=v.w;
  }
  double acc[8];
#pragma unroll
  for (int e = 0; e < 8; e++) acc[e] = 0.0;
  const float* wp = wr + (size_t)(lane * 16) * E_;   // w_router is [D][E]
#pragma unroll
  for (int i = 0; i < 16; i++) {
    float xs = xv[i];
#pragma unroll
    for (int e = 0; e < 8; e++) acc[e] += (double)xs * (double)wp[i*8 + e];
  }
  for (int off = 32; off > 0; off >>= 1) {
#pragma unroll
    for (int e = 0; e < 8; e++) acc[e] += __shfl_xor(acc[e], off, 64);
  }

  float l[8];
#pragma unroll
  for (int e = 0; e < 8; e++) l[e] = (float)acc[e];
  float m = l[0]; int best = 0;
#pragma unroll
  for (int e = 1; e < 8; e++) if (l[e] > m) { m = l[e]; best = e; }   // first-max tiebreak
  float p[8], sum = 0.f;
#pragma unroll
  for (int e = 0; e < 8; e++) { p[e] = expf(l[e] - m); sum += p[e]; }
  float inv = 1.f / sum;
#pragma unroll
  for (int e = 0; e < 8; e++) p[e] *= inv;
  float z    = m + logf(sum);
  float gate = inv;                      // softmax at argmax = exp(0)/sum

  __shared__ float s_cnt[8], s_prox[8], s_zsq[1];
  if (threadIdx.x < 8)  { s_cnt[threadIdx.x] = 0.f; s_prox[threadIdx.x] = 0.f; }
  if (threadIdx.x == 8) s_zsq[0] = 0.f;
  __syncthreads();
  if (lane == 0) {
    idx_buf[token]  = best;
    gate_buf[token] = gate;
    atomicAdd(&s_zsq[0], z * z);
    atomicAdd(&s_cnt[best], 1.f);
#pragma unroll
    for (int e = 0; e < 8; e++) atomicAdd(&s_prox[e], p[e]);
  }
  __syncthreads();
  if (threadIdx.x < 8) {
    atomicAdd(&stats[b*8 + threadIdx.x],      s_cnt[threadIdx.x]);
    atomicAdd(&stats[32 + b*8 + threadIdx.x], s_prox[threadIdx.x]);
  }
  if (threadIdx.x == 8) atomicAdd(&stats[64], s_zsq[0]);
}

// ---------------------------------------------------------------------------
// K2: per-(b,e) capacity scan + loss finalize (folded; stats ready since the
// router kernel completed before this launch).
// ---------------------------------------------------------------------------
__global__ __launch_bounds__(64) void pos_kernel(
    const int* __restrict__ idx_buf, int* __restrict__ slot_token,
    const float* __restrict__ stats, float* __restrict__ loss_out)
{
  int be = blockIdx.x;                 // 0..31
  int b = be >> 3, e = be & 7;
  int lane = threadIdx.x;
  int base = 0;
  int* out = slot_token + (size_t)(e * B_ + b) * C_;
  for (int n0 = 0; n0 < N_; n0 += 64) {
    int n = n0 + lane;
    bool match = (idx_buf[b * N_ + n] == e);
    unsigned long long mask = __ballot(match);
    int my = base + __popcll(mask & ((1ull << lane) - 1ull));
    if (match && my < C_) out[my] = b * N_ + n;
    base += __popcll(mask);
  }
  if (be == 0 && lane == 0) {
    float aux = 0.f;
    for (int i = 0; i < 32; i++) aux += stats[i] * stats[32 + i];
    aux *= 64.f / ((float)B_ * (float)N_ * (float)N_);   // E^2 / (B*N*N)
    loss_out[0] = aux;
    loss_out[1] = stats[64] / (float)(B_ * N_);
  }
}

// ---------------------------------------------------------------------------
// K3: gather+cast x rows into xe bf16 [E][M_][D]. One block per slot row.
// ---------------------------------------------------------------------------
__global__ __launch_bounds__(256) void gather_kernel(
    const float* __restrict__ x, const int* __restrict__ slot_token,
    unsigned short* __restrict__ xe)
{
  int row = blockIdx.x;                // 0..E*M_-1  == (e*B+b)*C + c
  int t = slot_token[row];
  int col = threadIdx.x * 4;
  ushort4 o;
  if (t >= 0) {
    float4 v = *(const float4*)(x + (size_t)t * D_ + col);
    o.x = f2bf(v.x); o.y = f2bf(v.y); o.z = f2bf(v.z); o.w = f2bf(v.w);
  } else {
    o.x = 0; o.y = 0; o.z = 0; o.w = 0;
  }
  *(ushort4*)(xe + (size_t)row * D_ + col) = o;
}

// ---------------------------------------------------------------------------
// K4: transpose+cast weights: in fp32 [E][R][Cc] -> out bf16 [E][Cc][R].
// 64x64 tile; coalesced reads/writes; LDS padded to 65.
// ---------------------------------------------------------------------------
__global__ __launch_bounds__(256) void transcast_kernel(
    const float* __restrict__ in, unsigned short* __restrict__ out, int R, int Cc)
{
  int e = blockIdx.z;
  const float* pin = in + (size_t)e * R * Cc;
  unsigned short* pout = out + (size_t)e * R * Cc;
  __shared__ float T[64][65];
  int r0 = blockIdx.y * 64, c0 = blockIdx.x * 64;
  {
    int row = threadIdx.x >> 2;               // 0..63
    int cb  = (threadIdx.x & 3) * 4;          // 0,4,8,12
#pragma unroll
    for (int p = 0; p < 4; p++) {
      int col = cb + p * 16;
      float4 v = *(const float4*)(pin + (size_t)(r0 + row) * Cc + c0 + col);
      T[row][col+0] = v.x; T[row][col+1] = v.y; T[row][col+2] = v.z; T[row][col+3] = v.w;
    }
  }
  __syncthreads();
  {
    int ocb = threadIdx.x >> 4;               // 0..15
    int or4 = (threadIdx.x & 15) * 4;         // 0..60
#pragma unroll
    for (int p = 0; p < 4; p++) {
      int oc = ocb + p * 16;
      ushort4 o;
      o.x = f2bf(T[or4+0][oc]); o.y = f2bf(T[or4+1][oc]);
      o.z = f2bf(T[or4+2][oc]); o.w = f2bf(T[or4+3][oc]);
      *(ushort4*)(pout + (size_t)(c0 + oc) * R + r0 + or4) = o;
    }
  }
}

// ---------------------------------------------------------------------------
// K5: grouped GEMM, R4b (resubmission of R4 -- container infra failure, no
// kernel verdict; source re-audited: barriers uniform, LDS 33 KiB x 4 = 132
// < 160 KiB, 32-bit offsets max ~10.5 MB, swizzle bijective per rule #21).
//
// OCCUPANCY EXPERIMENT. Evidence R0-R3: four structurally different
// inner-loop schedules (conflicts 1e7->0, barriers 8->2, prefetch 0.5->2
// tiles, register read-ahead) all land at 153-176 us with MfmaUtil ~21%,
// VALUBusy ~10%, HBM ~9%, Occupancy ~14%. Counter triad = latency-bound
// with nothing to hide stalls: since R1 only ONE 8-wave block per CU
// (128 KiB LDS), all waves share one barrier group. R4 tests the m97/m114
// mechanism cleanly: 4 INDEPENDENT blocks per CU cross-hide each other's
// lgkm/vmcnt/barrier stalls.
//
// Geometry: 128x128 tile, BK=32, 256 thr = 4 waves (2x2), per-wave 64x64,
// acc[4][4]. LDS = 2buf x 2op x 128x32 bf16 = 32 KiB (+1 KiB tok/gate)
// -> 4 blocks/CU, 16 waves/CU. __launch_bounds__(256,4) caps VGPR at 128
// (est ~115: acc 64 + frags 32 + addr).
//
// Schedule = T3-minimum 2-phase (issue next-tile stage, read frags, lgkm(0),
// setprio+16 MFMA, vmcnt(0), barrier). Stall-hiding comes from TLP, not
// intra-block pipelining.
//
// T2 swizzle re-derived for 64 B rows (BK=32): read chunk = quad ^ ((row>>1)&3)
// -> balanced 8-lane buckets per 16B slot pair (R1's analogous swizzle
// measured SQ_LDS_BANK_CONFLICT = 0). Staging pre-swizzles the GLOBAL
// source (LDS dest linear, m104/m173): src chunk = (lane&3) ^ ((lane>>3)&3).
//
// K accumulation order per acc unchanged (k ascending, 32 per MFMA) ->
// bitwise-identical output to R0-R3.
//
// Grids: GEMM1 = 8*32*10 = 2560 blocks (10/CU exact); GEMM2 = 8*8*10 = 640.
// T1 pinning kept: expert = blockIdx & 7 == XCD.
// ---------------------------------------------------------------------------
template<int EPI>
__global__ __launch_bounds__(256, 4) void gemm_kernel(
    const unsigned short* __restrict__ A,    // [E][M][K] bf16
    const unsigned short* __restrict__ BT,   // [E][Nn][K] bf16
    const float* __restrict__ bias,          // [E][Nn] fp32
    unsigned short* __restrict__ Hout,       // EPI=0
    float* __restrict__ Out,                 // EPI=1 (pre-zeroed d_out)
    const int* __restrict__ slot_token,     // EPI=1
    const float* __restrict__ gate_buf,     // EPI=1
    int M, int K, int Nn, int MT)            // MT = M/128 tiles
{
  int e  = blockIdx.x & 7;                  // expert == XCD (round-robin map)
  int s  = blockIdx.x >> 3;                 // slot within expert
  int m0 = (s % MT) * 128;                  // m-inner
  int n0 = (s / MT) * 128;                  // n-outer
  const unsigned short* Ae = A  + (size_t)e * M  * K;
  const unsigned short* Be = BT + (size_t)e * Nn * K;

  __shared__ __align__(16) unsigned short As[2][128 * 32];   // 16 KiB
  __shared__ __align__(16) unsigned short Bs[2][128 * 32];   // 16 KiB
  __shared__ int   s_tok[128];
  __shared__ float s_gate[128];

  int tid  = threadIdx.x;
  int lane = tid & 63;
  int w    = tid >> 6;                      // wave 0..3
  int wm   = (w >> 1) * 64;                 // wave row base within tile
  int wn   = (w & 1) * 64;                  // wave col base within tile
  int lr   = lane & 15;
  int quad = lane >> 4;
  // swizzled read chunk offset (elements): chunk = quad ^ ((row>>1)&3), row%16==lr
  int rch  = ((quad ^ ((lr >> 1) & 3)) << 3);

  if constexpr (EPI == 1) {
    if (tid < 128) {
      int t = slot_token[(size_t)e * M + m0 + tid];
      s_tok[tid]  = t;
      s_gate[tid] = (t >= 0) ? gate_buf[t] : 0.f;
    }
  }

  floatx4 acc[4][4];
#pragma unroll
  for (int i = 0; i < 4; i++)
#pragma unroll
    for (int j = 0; j < 4; j++) acc[i][j] = (floatx4){0.f, 0.f, 0.f, 0.f};

  // Staging: one gload_lds16 covers 16 rows x 32 k (1 KiB). lane -> row
  // base + (lane>>2), src chunk = (lane&3) ^ ((lane>>3)&3) [inverse swizzle;
  // (row>>1)&3 == (lane>>3)&3 since base%16==0]. LDS dest linear.
  // Per wave: 2 A loads (rows w*16, 64+w*16) + 2 B loads.
  unsigned kA   = (unsigned)K * 2;          // bytes per row
  unsigned soff = (unsigned)((lane & 3) ^ ((lane >> 3) & 3)) * 16u
                + (unsigned)(lane >> 2) * kA;
  unsigned aoff = (unsigned)(m0 + w * 16) * kA + soff;
  unsigned boff = (unsigned)(n0 + w * 16) * kA + soff;
  const char* AeC = (const char*)Ae;
  const char* BeC = (const char*)Be;

#define STAGE_A(dbuf) do { \
    gload_lds16((const unsigned short*)(AeC + aoff),           &As[dbuf][(w * 16) * 32]); \
    gload_lds16((const unsigned short*)(AeC + aoff + 64 * kA), &As[dbuf][(64 + w * 16) * 32]); \
    aoff += 64; } while (0)
#define STAGE_B(dbuf) do { \
    gload_lds16((const unsigned short*)(BeC + boff),           &Bs[dbuf][(w * 16) * 32]); \
    gload_lds16((const unsigned short*)(BeC + boff + 64 * kA), &Bs[dbuf][(64 + w * 16) * 32]); \
    boff += 64; } while (0)

  int nt = K >> 5;                          // K-tiles of 32
  // Prologue: tile0 -> buf0, drain, publish.
  STAGE_A(0); STAGE_B(0);
  asm volatile("s_waitcnt vmcnt(0)" ::: "memory");
  __builtin_amdgcn_s_barrier();

  for (int t = 0; t < nt; ++t) {
    int cur = t & 1, nxt = cur ^ 1;
    // Issue next tile's staging first (loads start HBM/L2 latency early).
    // buf[nxt] holds tile t-1: every wave finished reading it before the
    // end-of-iter-(t-1) barrier (lgkmcnt(0) precedes it) -> overwrite safe.
    if (t + 1 < nt) { STAGE_A(nxt); STAGE_B(nxt); }
    short8 a[4], b[4];
#pragma unroll
    for (int m = 0; m < 4; ++m)
      a[m] = *(const short8*)&As[cur][(wm + m * 16 + lr) * 32 + rch];
#pragma unroll
    for (int n = 0; n < 4; ++n)
      b[n] = *(const short8*)&Bs[cur][(wn + n * 16 + lr) * 32 + rch];
    asm volatile("s_waitcnt lgkmcnt(0)" ::: "memory");
    __builtin_amdgcn_sched_barrier(0);
    __builtin_amdgcn_s_setprio(1);
#pragma unroll
    for (int m = 0; m < 4; ++m)
#pragma unroll
      for (int n = 0; n < 4; ++n)
        acc[m][n] = __builtin_amdgcn_mfma_f32_16x16x32_bf16(a[m], b[n], acc[m][n], 0, 0, 0);
    __builtin_amdgcn_s_setprio(0);
    // Drain tile t+1's 4 own loads (the only in-flight ones), then publish.
    if (t + 1 < nt) asm volatile("s_waitcnt vmcnt(0)" ::: "memory");
    __builtin_amdgcn_s_barrier();
  }
#undef STAGE_A
#undef STAGE_B

  // Epilogue. C/D layout: col = lane&15, row = quad*4 + reg (m89-verified).
#pragma unroll
  for (int m = 0; m < 4; ++m) {
    int rloc = wm + m * 16 + quad * 4;      // block-local row base
#pragma unroll
    for (int n = 0; n < 4; ++n) {
      int col = n0 + wn + n * 16 + lr;
      float bz = bias[(size_t)e * Nn + col];
      if constexpr (EPI == 0) {
        size_t base = (size_t)e * M * Nn + (size_t)(m0 + rloc) * Nn + col;
#pragma unroll
        for (int r = 0; r < 4; r++)
          Hout[base + (size_t)r * Nn] = f2bf(gelu_fast(acc[m][n][r] + bz));
      } else {
#pragma unroll
        for (int r = 0; r < 4; r++) {
          int t = s_tok[rloc + r];
          if (t >= 0)
            Out[(size_t)t * D_ + col] = s_gate[rloc + r] * (acc[m][n][r] + bz);
        }
      }
    }
  }
}

// ---------------------------------------------------------------------------
extern "C" void kernel_launch(void* const* d_in, const int* in_sizes, int n_in,
                              void* d_out, int out_size, void* d_ws, size_t ws_size,
                              hipStream_t stream)
{
  (void)in_sizes; (void)n_in; (void)ws_size;
  const float* x  = (const float*)d_in[0];
  const float* wr = (const float*)d_in[1];
  const float* w1 = (const float*)d_in[2];
  const float* b1 = (const float*)d_in[3];
  const float* w2 = (const float*)d_in[4];
  const float* b2 = (const float*)d_in[5];
  float* out = (float*)d_out;

  // ws layout (~172 MB total)
  char* ws = (char*)d_ws;
  int*   idx_buf  = (int*)(ws + 0);              // 32 KB
  float* gate_buf = (float*)(ws + 32768);        // 32 KB
  float* stats    = (float*)(ws + 65536);        // 1 KB
  int*   slot_tok = (int*)(ws + 66560);          // 40 KB
  unsigned short* xe  = (unsigned short*)(ws + 107520);    // 20.97 MB
  unsigned short* wbf = (unsigned short*)(ws + 21079040);  // 67.1 MB (w1 then w2)
  unsigned short* hbf = (unsigned short*)(ws + 88187904);  // 83.9 MB; end 172073984

  hipMemsetAsync(d_out, 0, (size_t)out_size * 4, stream);       // dropped tokens -> 0
  hipMemsetAsync(stats, 0, 1024, stream);
  hipMemsetAsync(slot_tok, 0xFF, (size_t)E_ * B_ * C_ * 4, stream);  // -1 = empty slot

  router_kernel<<<(B_ * N_) / 4, 256, 0, stream>>>(x, wr, idx_buf, gate_buf, stats);
  pos_kernel<<<B_ * E_, 64, 0, stream>>>(idx_buf, slot_tok, stats,
                                         out + (size_t)B_ * N_ * D_);
  gather_kernel<<<E_ * M_, 256, 0, stream>>>(x, slot_tok, xe);

  // w1 [E][D][H] -> wbf [E][H][D]
  transcast_kernel<<<dim3(H_ / 64, D_ / 64, E_), 256, 0, stream>>>(w1, wbf, D_, H_);
  // h = gelu(xe @ w1 + b1): M=1280, K=1024, Nn=4096; grid = E * (32n x 10m)
  gemm_kernel<0><<<E_ * (H_ / 128) * (M_ / 128), 256, 0, stream>>>(
      xe, wbf, b1, hbf, nullptr, nullptr, nullptr, M_, D_, H_, M_ / 128);
  // w2 [E][H][D] -> wbf [E][D][H]  (reuse buffer; stream-serialized after GEMM1)
  transcast_kernel<<<dim3(D_ / 64, H_ / 64, E_), 256, 0, stream>>>(w2, wbf, H_, D_);
  // out = gate * (h @ w2 + b2): M=1280, K=4096, Nn=1024; grid = E * (8n x 10m)
  gemm_kernel<1><<<E_ * (D_ / 128) * (M_ / 128), 256, 0, stream>>>(
      hbf, wbf, b2, nullptr, out, slot_tok, gate_buf, M_, H_, D_, M_ / 128);
}